// Round 1
// baseline (487.123 us; speedup 1.0000x reference)
//
#include <hip/hip_runtime.h>
#include <hip/hip_bf16.h>
#include <cstdint>
#include <cstdio>

typedef unsigned short u16;
typedef unsigned int   u32;
typedef __attribute__((ext_vector_type(8))) short bf16x8;   // 8 bf16 (4 VGPRs), per guide §3
typedef __attribute__((ext_vector_type(4))) float f32x4;
typedef __attribute__((ext_vector_type(4))) u16   u16x4;

#define GLOBAL_AS __attribute__((address_space(1)))
#define LDS_AS    __attribute__((address_space(3)))

static __device__ __forceinline__ u16 f2bf(float f) {
  u32 u = __builtin_bit_cast(u32, f);
  u = (u + 0x7fffu + ((u >> 16) & 1u)) >> 16;   // RNE
  return (u16)u;
}

static __device__ __forceinline__ void gload_lds16(const void* g, void* l) {
  __builtin_amdgcn_global_load_lds((GLOBAL_AS u32*)g, (LDS_AS u32*)l, 16, 0, 0);
}

// ---------------------------------------------------------------------------
// k_cvt: dst[r][dcol+c] = bf16(src[r][c0+c]) for r<rows_src else 0. 4 elems/thread.
__global__ void k_cvt(const float* __restrict__ src, int ld, int c0,
                      int rows_src, int cols4, int total4,
                      u16* __restrict__ dst, int ldd, int dcol) {
  int gid = blockIdx.x * 256 + threadIdx.x;
  if (gid >= total4) return;
  int r = gid / cols4;
  int c = (gid - r * cols4) * 4;
  u16x4 o = {0, 0, 0, 0};
  if (r < rows_src) {
    const float4 v = *(const float4*)&src[(size_t)r * ld + c0 + c];
    o[0] = f2bf(v.x); o[1] = f2bf(v.y); o[2] = f2bf(v.z); o[3] = f2bf(v.w);
  }
  *(u16x4*)&dst[(size_t)r * ldd + dcol + c] = o;
}

// ---------------------------------------------------------------------------
// k_init: out[bi][0]=EPS; out[bi][1+n]=rough[bi][n]+bout
__global__ void k_init(const float* __restrict__ rough,
                       const float* __restrict__ bout,
                       float* __restrict__ out) {
  int i = blockIdx.x * 256 + threadIdx.x;
  if (i >= 1024 * 65) return;
  int bi = i / 65, c = i - bi * 65;
  out[i] = (c == 0) ? 1e-7f : rough[bi * 64 + c - 1] + bout[0];
}

// ---------------------------------------------------------------------------
// k_build_cmat: Cmat[lr][k] = bf16(a[bi][k]*b[idx][k]) for k<1024, bf16(pw[r][k-1024]) else.
// One chunk of 16384 rows; 4 elems/thread; 272 = 1088/4 groups per row.
__global__ void k_build_cmat(const float* __restrict__ ments,
                             const float* __restrict__ allm,
                             const float* __restrict__ pw,
                             const int* __restrict__ topidx,
                             u16* __restrict__ Cmat, int r0) {
  int gid = blockIdx.x * 256 + threadIdx.x;   // 16384*272 exact
  int lr = gid / 272;
  int c4 = gid - lr * 272;
  int r  = r0 + lr;
  int bi = r >> 6;
  u16x4 o;
  if (c4 < 256) {
    int k   = c4 * 4;
    int idx = topidx[r];
    float4 a = *(const float4*)&ments[(size_t)bi * 1024 + k];
    float4 b = *(const float4*)&allm[(size_t)idx * 1024 + k];
    o[0] = f2bf(a.x * b.x); o[1] = f2bf(a.y * b.y);
    o[2] = f2bf(a.z * b.z); o[3] = f2bf(a.w * b.w);
  } else {
    int k = (c4 - 256) * 4;
    float4 p = *(const float4*)&pw[(size_t)r * 64 + k];
    o[0] = f2bf(p.x); o[1] = f2bf(p.y); o[2] = f2bf(p.z); o[3] = f2bf(p.w);
  }
  *(u16x4*)&Cmat[(size_t)lr * 1088 + c4 * 4] = o;
}

// ---------------------------------------------------------------------------
// gemm_nt: C[M,N] = A[M,K] @ B[N,K]^T, bf16 inputs, f32 accumulate.
// m97 structure: 128x128 tile, BK=64, 256 thr (4 waves 2x2), global_load_lds w=16.
// FUSED: epilogue adds Aproj/Bproj/b1, leaky_relu, *Wout, row-reduce, atomicAdd out.
template<bool FUSED>
__global__ __launch_bounds__(256)
void gemm_nt(const u16* __restrict__ A, int lda,
             const u16* __restrict__ B, int ldb, int Ksteps,
             float* __restrict__ C, int ldc,
             const float* __restrict__ Aproj, const float* __restrict__ Bproj,
             const float* __restrict__ b1, const float* __restrict__ Wout,
             const int* __restrict__ topidx, float* __restrict__ out, int r0) {
  __shared__ u16 As[128 * 64];
  __shared__ u16 Bs[128 * 64];
  const int t = threadIdx.x;
  const int w = t >> 6, l = t & 63;
  const int wr = w >> 1, wc = w & 1;
  const int brow = blockIdx.x * 128;
  const int bcol = blockIdx.y * 128;
  const int srow = t >> 3;          // 0..31
  const int scol = (t & 7) * 8;     // element col in K-tile

  f32x4 acc[4][4] = {};

  for (int ks = 0; ks < Ksteps; ++ks) {
    const int kb = ks * 64;
#pragma unroll
    for (int q = 0; q < 4; ++q) {
      int r = q * 32 + srow;
      gload_lds16(A + (size_t)(brow + r) * lda + kb + scol, &As[r * 64 + scol]);
      gload_lds16(B + (size_t)(bcol + r) * ldb + kb + scol, &Bs[r * 64 + scol]);
    }
    __syncthreads();
#pragma unroll
    for (int kk = 0; kk < 2; ++kk) {
      bf16x8 af[4], bfr[4];
#pragma unroll
      for (int m = 0; m < 4; ++m)
        af[m] = *(const bf16x8*)&As[(wr * 64 + m * 16 + (l & 15)) * 64 + kk * 32 + (l >> 4) * 8];
#pragma unroll
      for (int n = 0; n < 4; ++n)
        bfr[n] = *(const bf16x8*)&Bs[(wc * 64 + n * 16 + (l & 15)) * 64 + kk * 32 + (l >> 4) * 8];
#pragma unroll
      for (int m = 0; m < 4; ++m)
#pragma unroll
        for (int n = 0; n < 4; ++n)
          acc[m][n] = __builtin_amdgcn_mfma_f32_16x16x32_bf16(af[m], bfr[n], acc[m][n], 0, 0, 0);
    }
    __syncthreads();
  }

  if constexpr (FUSED) {
    const int cb = bcol + wc * 64;
    float b1c[4], wo[4];
#pragma unroll
    for (int n = 0; n < 4; ++n) {
      int col = cb + n * 16 + (l & 15);
      b1c[n] = b1[col];
      wo[n]  = Wout[col];
    }
#pragma unroll
    for (int m = 0; m < 4; ++m) {
#pragma unroll
      for (int reg = 0; reg < 4; ++reg) {
        int lrow = brow + wr * 64 + m * 16 + (l >> 4) * 4 + reg;  // row in chunk
        int gr = r0 + lrow;
        int bi = gr >> 6;
        int mi = topidx[gr];
        float s = 0.f;
#pragma unroll
        for (int n = 0; n < 4; ++n) {
          int col = cb + n * 16 + (l & 15);
          float v = acc[m][n][reg] + Aproj[(size_t)bi * 1024 + col]
                  + Bproj[(size_t)mi * 1024 + col] + b1c[n];
          v = v > 0.f ? v : 0.01f * v;          // leaky_relu(0.01)
          s += v * wo[n];
        }
        s += __shfl_xor(s, 1);
        s += __shfl_xor(s, 2);
        s += __shfl_xor(s, 4);
        s += __shfl_xor(s, 8);
        if ((l & 15) == 0)
          atomicAdd(&out[bi * 65 + 1 + (gr & 63)], s);
      }
    }
  } else {
#pragma unroll
    for (int m = 0; m < 4; ++m)
#pragma unroll
      for (int n = 0; n < 4; ++n)
#pragma unroll
        for (int reg = 0; reg < 4; ++reg) {
          int row = brow + wr * 64 + m * 16 + (l >> 4) * 4 + reg;
          int col = bcol + wc * 64 + n * 16 + (l & 15);
          C[(size_t)row * ldc + col] = acc[m][n][reg];
        }
  }
}

// ---------------------------------------------------------------------------
extern "C" void kernel_launch(void* const* d_in, const int* in_sizes, int n_in,
                              void* d_out, int out_size, void* d_ws, size_t ws_size,
                              hipStream_t stream) {
  const float* allm  = (const float*)d_in[0];   // [10000,1024]
  const float* ments = (const float*)d_in[1];   // [1024,1024]
  const float* pw    = (const float*)d_in[2];   // [1024,64,64]
  const int*   tidx  = (const int*)d_in[3];     // [1024,64]
  const float* rough = (const float*)d_in[4];   // [1024,64]
  const float* W1    = (const float*)d_in[5];   // [1024,3136]
  const float* b1    = (const float*)d_in[6];   // [1024]
  const float* Wout  = (const float*)d_in[7];   // [1,1024]
  const float* bout  = (const float*)d_in[8];   // [1]
  float* out = (float*)d_out;                   // [1024,65]

  const int CHUNK = 16384;
  // scratch layout
  u16* A16    = (u16*)d_ws;                 // 1024*1024
  u16* allm16 = A16 + 1024 * 1024;          // 10240*1024 (rows>=10000 zero)
  u16* W1a    = allm16 + 10240 * 1024;      // 1024*1024
  u16* W1b    = W1a + 1024 * 1024;          // 1024*1024
  u16* W1cp   = W1b + 1024 * 1024;          // 1024*1088
  float* Aproj = (float*)(W1cp + 1024 * 1088);  // 1024*1024 f32
  float* Bproj = Aproj + 1024 * 1024;           // 10240*1024 f32
  u16* Cmat   = (u16*)(Bproj + 10240 * 1024);   // CHUNK*1088 bf16

  size_t need = (size_t)2 * (1024*1024 + 10240*1024 + 1024*1024 + 1024*1024 + 1024*1088)
              + (size_t)4 * (1024*1024 + 10240*1024)
              + (size_t)2 * CHUNK * 1088;
  if (ws_size < need) {
    fprintf(stderr, "kernel_launch: ws_size %zu < needed %zu\n", ws_size, need);
    return;
  }

  // --- conversions / weight splits (bf16) ---
  {
    int t4;
    t4 = 1024 * 256;                               // W1a
    k_cvt<<<(t4 + 255) / 256, 256, 0, stream>>>(W1, 3136, 0,    1024, 256, t4, W1a, 1024, 0);
    k_cvt<<<(t4 + 255) / 256, 256, 0, stream>>>(W1, 3136, 1024, 1024, 256, t4, W1b, 1024, 0);
    k_cvt<<<(t4 + 255) / 256, 256, 0, stream>>>(W1, 3136, 2048, 1024, 256, t4, W1cp, 1088, 0);
    t4 = 1024 * 16;                                // W1p -> W1cp cols 1024..1087
    k_cvt<<<(t4 + 255) / 256, 256, 0, stream>>>(W1, 3136, 3072, 1024, 16, t4, W1cp, 1088, 1024);
    t4 = 1024 * 256;                               // mentions_batch
    k_cvt<<<(t4 + 255) / 256, 256, 0, stream>>>(ments, 1024, 0, 1024, 256, t4, A16, 1024, 0);
    t4 = 10240 * 256;                              // all_mentions (pad to 10240)
    k_cvt<<<(t4 + 255) / 256, 256, 0, stream>>>(allm, 1024, 0, 10000, 256, t4, allm16, 1024, 0);
  }

  // --- projection GEMMs: Aproj = ments@W1a^T, Bproj = allm@W1b^T ---
  gemm_nt<false><<<dim3(8, 8), 256, 0, stream>>>(A16, 1024, W1a, 1024, 16, Aproj, 1024,
                                                 nullptr, nullptr, nullptr, nullptr, nullptr, nullptr, 0);
  gemm_nt<false><<<dim3(80, 8), 256, 0, stream>>>(allm16, 1024, W1b, 1024, 16, Bproj, 1024,
                                                  nullptr, nullptr, nullptr, nullptr, nullptr, nullptr, 0);

  // --- init out with EPS column and rough+bout ---
  k_init<<<260, 256, 0, stream>>>(rough, bout, out);

  // --- chunked: build Cmat = [a*b | pw] bf16, then fused GEMM+epilogue ---
  for (int c = 0; c < 4; ++c) {
    int r0 = c * CHUNK;
    k_build_cmat<<<(CHUNK * 272) / 256, 256, 0, stream>>>(ments, allm, pw, tidx, Cmat, r0);
    gemm_nt<true><<<dim3(CHUNK / 128, 8), 256, 0, stream>>>(Cmat, 1088, W1cp, 1088, 17,
                                                            nullptr, 0,
                                                            Aproj, Bproj, b1, Wout, tidx, out, r0);
  }
}

// Round 2
// 435.505 us; speedup vs baseline: 1.1185x; 1.1185x over previous
//
#include <hip/hip_runtime.h>
#include <hip/hip_bf16.h>
#include <cstdint>
#include <cstdio>

typedef unsigned short u16;
typedef unsigned int   u32;
typedef __attribute__((ext_vector_type(8))) short bf16x8;   // 8 bf16 (4 VGPRs)
typedef __attribute__((ext_vector_type(4))) float f32x4;
typedef __attribute__((ext_vector_type(4))) u16   u16x4;

#define GLOBAL_AS __attribute__((address_space(1)))
#define LDS_AS    __attribute__((address_space(3)))

static __device__ __forceinline__ u16 f2bf(float f) {
  u32 u = __builtin_bit_cast(u32, f);
  u = (u + 0x7fffu + ((u >> 16) & 1u)) >> 16;   // RNE
  return (u16)u;
}
static __device__ __forceinline__ float bf2f(u16 v) {
  return __builtin_bit_cast(float, (u32)v << 16);
}

static __device__ __forceinline__ void gload_lds16(const void* g, void* l) {
  __builtin_amdgcn_global_load_lds((GLOBAL_AS u32*)g, (LDS_AS u32*)l, 16, 0, 0);
}

// ---------------------------------------------------------------------------
// k_cvt: dst[r][dcol+c] = bf16(src[r][c0+c]) for r<rows_src else 0. 4 elems/thread.
__global__ void k_cvt(const float* __restrict__ src, int ld, int c0,
                      int rows_src, int cols4, int total4,
                      u16* __restrict__ dst, int ldd, int dcol) {
  int gid = blockIdx.x * 256 + threadIdx.x;
  if (gid >= total4) return;
  int r = gid / cols4;
  int c = (gid - r * cols4) * 4;
  u16x4 o = {0, 0, 0, 0};
  if (r < rows_src) {
    const float4 v = *(const float4*)&src[(size_t)r * ld + c0 + c];
    o[0] = f2bf(v.x); o[1] = f2bf(v.y); o[2] = f2bf(v.z); o[3] = f2bf(v.w);
  }
  *(u16x4*)&dst[(size_t)r * ldd + dcol + c] = o;
}

// ---------------------------------------------------------------------------
// k_init: out[bi][0]=EPS; out[bi][1+n]=rough[bi][n]+bout
__global__ void k_init(const float* __restrict__ rough,
                       const float* __restrict__ bout,
                       float* __restrict__ out) {
  int i = blockIdx.x * 256 + threadIdx.x;
  if (i >= 1024 * 65) return;
  int bi = i / 65, c = i - bi * 65;
  out[i] = (c == 0) ? 1e-7f : rough[bi * 64 + c - 1] + bout[0];
}

// ---------------------------------------------------------------------------
// k_build_cmat: Cmat[lr][k] = bf16(a[bi][k]*b[idx][k]) k<1024; bf16(pw) else.
__global__ void k_build_cmat(const float* __restrict__ ments,
                             const float* __restrict__ allm,
                             const float* __restrict__ pw,
                             const int* __restrict__ topidx,
                             u16* __restrict__ Cmat, int r0) {
  int gid = blockIdx.x * 256 + threadIdx.x;   // 16384*272 exact
  int lr = gid / 272;
  int c4 = gid - lr * 272;
  int r  = r0 + lr;
  int bi = r >> 6;
  u16x4 o;
  if (c4 < 256) {
    int k   = c4 * 4;
    int idx = topidx[r];
    float4 a = *(const float4*)&ments[(size_t)bi * 1024 + k];
    float4 b = *(const float4*)&allm[(size_t)idx * 1024 + k];
    o[0] = f2bf(a.x * b.x); o[1] = f2bf(a.y * b.y);
    o[2] = f2bf(a.z * b.z); o[3] = f2bf(a.w * b.w);
  } else {
    int k = (c4 - 256) * 4;
    float4 p = *(const float4*)&pw[(size_t)r * 64 + k];
    o[0] = f2bf(p.x); o[1] = f2bf(p.y); o[2] = f2bf(p.z); o[3] = f2bf(p.w);
  }
  *(u16x4*)&Cmat[(size_t)lr * 1088 + c4 * 4] = o;
}

// ---------------------------------------------------------------------------
// gemm_nt: C[M,N] = A[M,K] @ B[N,K]^T, bf16 in, f32 acc.
// 128x128 tile, BK=64, 256 thr (4 waves 2x2), global_load_lds w=16.
// T2 both-sides swizzle (rule #21): LDS dest linear; SOURCE granule g^=(r&7);
// ds_read applies the same XOR. Kills the 8-way bank conflict of row-major [128][64].
// FUSED epilogue: + Aproj/Bproj(bf16 gather) + b1, leaky_relu, *Wout, 16-lane
// shfl reduce, atomicAdd into out. Non-fused: writes bf16 C.
template<bool FUSED>
__global__ __launch_bounds__(256)
void gemm_nt(const u16* __restrict__ A, int lda,
             const u16* __restrict__ B, int ldb, int Ksteps,
             u16* __restrict__ C, int ldc,
             const u16* __restrict__ Aproj, const u16* __restrict__ Bproj,
             const float* __restrict__ b1, const float* __restrict__ Wout,
             const int* __restrict__ topidx, float* __restrict__ out, int r0) {
  __shared__ u16 As[128 * 64];
  __shared__ u16 Bs[128 * 64];
  const int t = threadIdx.x;
  const int w = t >> 6, l = t & 63;
  const int wr = w >> 1, wc = w & 1;
  const int brow = blockIdx.x * 128;
  const int bcol = blockIdx.y * 128;
  const int srow = t >> 3;                         // 0..31 within quarter
  const int scol = (t & 7) * 8;                    // linear LDS dest col (elems)
  const int gsw  = (((t & 7) ^ ((t >> 3) & 7))) * 8;  // swizzled SOURCE col

  f32x4 acc[4][4] = {};

  for (int ks = 0; ks < Ksteps; ++ks) {
    const int kb = ks * 64;
#pragma unroll
    for (int q = 0; q < 4; ++q) {
      int r = q * 32 + srow;                       // r&7 == (t>>3)&7
      gload_lds16(A + (size_t)(brow + r) * lda + kb + gsw, &As[r * 64 + scol]);
      gload_lds16(B + (size_t)(bcol + r) * ldb + kb + gsw, &Bs[r * 64 + scol]);
    }
    __syncthreads();
#pragma unroll
    for (int kk = 0; kk < 2; ++kk) {
      bf16x8 af[4], bfr[4];
      const int pg = ((kk * 4 + (l >> 4)) ^ (l & 7)) * 8;  // swizzled read col
#pragma unroll
      for (int m = 0; m < 4; ++m)
        af[m] = *(const bf16x8*)&As[(wr * 64 + m * 16 + (l & 15)) * 64 + pg];
#pragma unroll
      for (int n = 0; n < 4; ++n)
        bfr[n] = *(const bf16x8*)&Bs[(wc * 64 + n * 16 + (l & 15)) * 64 + pg];
#pragma unroll
      for (int m = 0; m < 4; ++m)
#pragma unroll
        for (int n = 0; n < 4; ++n)
          acc[m][n] = __builtin_amdgcn_mfma_f32_16x16x32_bf16(af[m], bfr[n], acc[m][n], 0, 0, 0);
    }
    __syncthreads();
  }

  if constexpr (FUSED) {
    const int cb = bcol + wc * 64;
    float b1c[4], wo[4];
#pragma unroll
    for (int n = 0; n < 4; ++n) {
      int col = cb + n * 16 + (l & 15);
      b1c[n] = b1[col];
      wo[n]  = Wout[col];
    }
#pragma unroll
    for (int m = 0; m < 4; ++m) {
#pragma unroll
      for (int reg = 0; reg < 4; ++reg) {
        int lrow = brow + wr * 64 + m * 16 + (l >> 4) * 4 + reg;  // row in chunk
        int gr = r0 + lrow;
        int bi = gr >> 6;
        int mi = topidx[gr];
        float s = 0.f;
#pragma unroll
        for (int n = 0; n < 4; ++n) {
          int col = cb + n * 16 + (l & 15);
          float v = acc[m][n][reg] + bf2f(Aproj[(size_t)bi * 1024 + col])
                  + bf2f(Bproj[(size_t)mi * 1024 + col]) + b1c[n];
          v = v > 0.f ? v : 0.01f * v;          // leaky_relu(0.01)
          s += v * wo[n];
        }
        s += __shfl_xor(s, 1);
        s += __shfl_xor(s, 2);
        s += __shfl_xor(s, 4);
        s += __shfl_xor(s, 8);
        if ((l & 15) == 0)
          atomicAdd(&out[bi * 65 + 1 + (gr & 63)], s);
      }
    }
  } else {
#pragma unroll
    for (int m = 0; m < 4; ++m)
#pragma unroll
      for (int n = 0; n < 4; ++n)
#pragma unroll
        for (int reg = 0; reg < 4; ++reg) {
          int row = brow + wr * 64 + m * 16 + (l >> 4) * 4 + reg;
          int col = bcol + wc * 64 + n * 16 + (l & 15);
          C[(size_t)row * ldc + col] = f2bf(acc[m][n][reg]);
        }
  }
}

// ---------------------------------------------------------------------------
extern "C" void kernel_launch(void* const* d_in, const int* in_sizes, int n_in,
                              void* d_out, int out_size, void* d_ws, size_t ws_size,
                              hipStream_t stream) {
  const float* allm  = (const float*)d_in[0];   // [10000,1024]
  const float* ments = (const float*)d_in[1];   // [1024,1024]
  const float* pw    = (const float*)d_in[2];   // [1024,64,64]
  const int*   tidx  = (const int*)d_in[3];     // [1024,64]
  const float* rough = (const float*)d_in[4];   // [1024,64]
  const float* W1    = (const float*)d_in[5];   // [1024,3136]
  const float* b1    = (const float*)d_in[6];   // [1024]
  const float* Wout  = (const float*)d_in[7];   // [1,1024]
  const float* bout  = (const float*)d_in[8];   // [1]
  float* out = (float*)d_out;                   // [1024,65]

  const int CHUNK = 16384;
  // scratch layout (all u16 now)
  u16* A16    = (u16*)d_ws;                 // 1024*1024
  u16* allm16 = A16 + 1024 * 1024;          // 10240*1024 (rows>=10000 zero)
  u16* W1a    = allm16 + 10240 * 1024;      // 1024*1024
  u16* W1b    = W1a + 1024 * 1024;          // 1024*1024
  u16* W1cp   = W1b + 1024 * 1024;          // 1024*1088
  u16* Aproj  = W1cp + 1024 * 1088;         // 1024*1024 bf16
  u16* Bproj  = Aproj + 1024 * 1024;        // 10240*1024 bf16
  u16* Cmat   = Bproj + 10240 * 1024;       // CHUNK*1088 bf16

  size_t need = (size_t)2 * ((size_t)1024*1024 + 10240*1024 + 1024*1024 + 1024*1024
              + 1024*1088 + 1024*1024 + 10240*1024 + (size_t)CHUNK*1088);
  if (ws_size < need) {
    fprintf(stderr, "kernel_launch: ws_size %zu < needed %zu\n", ws_size, need);
    return;
  }

  // --- conversions / weight splits (bf16) ---
  {
    int t4;
    t4 = 1024 * 256;                               // W1a
    k_cvt<<<(t4 + 255) / 256, 256, 0, stream>>>(W1, 3136, 0,    1024, 256, t4, W1a, 1024, 0);
    k_cvt<<<(t4 + 255) / 256, 256, 0, stream>>>(W1, 3136, 1024, 1024, 256, t4, W1b, 1024, 0);
    k_cvt<<<(t4 + 255) / 256, 256, 0, stream>>>(W1, 3136, 2048, 1024, 256, t4, W1cp, 1088, 0);
    t4 = 1024 * 16;                                // W1p -> W1cp cols 1024..1087
    k_cvt<<<(t4 + 255) / 256, 256, 0, stream>>>(W1, 3136, 3072, 1024, 16, t4, W1cp, 1088, 1024);
    t4 = 1024 * 256;                               // mentions_batch
    k_cvt<<<(t4 + 255) / 256, 256, 0, stream>>>(ments, 1024, 0, 1024, 256, t4, A16, 1024, 0);
    t4 = 10240 * 256;                              // all_mentions (pad to 10240)
    k_cvt<<<(t4 + 255) / 256, 256, 0, stream>>>(allm, 1024, 0, 10000, 256, t4, allm16, 1024, 0);
  }

  // --- projection GEMMs: Aproj = ments@W1a^T, Bproj = allm@W1b^T (bf16 out) ---
  gemm_nt<false><<<dim3(8, 8), 256, 0, stream>>>(A16, 1024, W1a, 1024, 16, Aproj, 1024,
                                                 nullptr, nullptr, nullptr, nullptr, nullptr, nullptr, 0);
  gemm_nt<false><<<dim3(80, 8), 256, 0, stream>>>(allm16, 1024, W1b, 1024, 16, Bproj, 1024,
                                                  nullptr, nullptr, nullptr, nullptr, nullptr, nullptr, 0);

  // --- init out with EPS column and rough+bout ---
  k_init<<<260, 256, 0, stream>>>(rough, bout, out);

  // --- chunked: build Cmat = [a*b | pw] bf16, then fused GEMM+epilogue ---
  for (int c = 0; c < 4; ++c) {
    int r0 = c * CHUNK;
    k_build_cmat<<<(CHUNK * 272) / 256, 256, 0, stream>>>(ments, allm, pw, tidx, Cmat, r0);
    gemm_nt<true><<<dim3(CHUNK / 128, 8), 256, 0, stream>>>(Cmat, 1088, W1cp, 1088, 17,
                                                            nullptr, 0,
                                                            Aproj, Bproj, b1, Wout, tidx, out, r0);
  }
}